// Round 6
// baseline (524.887 us; speedup 1.0000x reference)
//
#include <hip/hip_runtime.h>
#include <hip/hip_bf16.h>
#include <stdint.h>
#include <stddef.h>

// GroupViT assign-attention, MI355X/gfx950. All I/O fp32.
// Identities:
//   raw_attn = (q @ k_w) . key_n + q . k_b          -> no k-projection GEMM
//   fwd attn value = one_hot(argmax)/(cnt+1)        -> no v-projection GEMM
//   out_pre = (sum_assigned key_n)/(cnt+1) @ v_w^T + cnt/(cnt+1) v_b
// R2 lesson: runtime index into register array kills SROA -> scratch spill.
// R3 lesson: 12.6M fp32 atomicAdds cost >100us -> counting-sort (perm) + gather.
// R5 lesson: contiguous key streaming fixes DRAM page locality; fp16 double
//   split (scheme err ~6e-8) is the only split that doesn't flip argmax ties.
// R7 lesson: 8 waves in 144KB LDS ok but 96 ds_read_b128/wave/chunk -> LDS
//   serialization ~= HBM stream time; stacked, not hidden.
// R9 (this round): k_attn: A-operand CACHED IN REGISTERS (24 s16x8/wave,
//   K-split across wave pairs), no As LDS tile; Bs holds kh+km (96KB) so all
//   72 MFMA/chunk run in ONE region; K-half partials via 16KB LDS scratch.
//   24 B-reads/wave/chunk (was 96). k_bias folded into k_qtf; cnt-zeroing
//   folded into k_w2.

using bf16 = __hip_bfloat16;
typedef __attribute__((ext_vector_type(4))) float f32x4;
typedef __attribute__((ext_vector_type(8))) short s16x8;
typedef __attribute__((ext_vector_type(4))) short s16x4;
typedef _Float16 f16x8 __attribute__((ext_vector_type(8)));

#define B_  32
#define G_  64
#define N_  4096
#define C_  384
#define CAP 2048   // perm bucket capacity (counts ~64 avg; 2048 is >>max)
#define SCALE 0.05103103630798287f   // 384^-0.5

__device__ __forceinline__ float us2f(unsigned short u){
  union { unsigned int i; float f; } v; v.i = ((unsigned int)u) << 16; return v.f;
}
__device__ __forceinline__ unsigned short f2us(float f){
  bf16 h = __float2bfloat16(f);
  return __builtin_bit_cast(unsigned short, h);
}
// fp16 (IEEE half) helpers, RNE.
__device__ __forceinline__ unsigned short f2h(float f){
  _Float16 h = (_Float16)f;
  return __builtin_bit_cast(unsigned short, h);
}
__device__ __forceinline__ float h2f(unsigned short u){
  return (float)__builtin_bit_cast(_Float16, u);
}

__device__ __forceinline__ f32x4 mfma16(s16x8 a, s16x8 b, f32x4 c){
  return __builtin_amdgcn_mfma_f32_16x16x32_bf16(a, b, c, 0, 0, 0);
}
__device__ __forceinline__ f32x4 mfma16h(s16x8 a, s16x8 b, f32x4 c){
  return __builtin_amdgcn_mfma_f32_16x16x32_f16(
      __builtin_bit_cast(f16x8, a), __builtin_bit_cast(f16x8, b), c, 0, 0, 0);
}

// Swizzled LDS layouts: 16B granule q XOR'd with row&7 (bank-spread).
__device__ __forceinline__ int loff(int m, int q){ return m*64 + ((q ^ (m & 7)) << 3); }
__device__ __forceinline__ int loff384(int m, int q){ return m*384 + ((q ^ (m & 7)) << 3); }

// Stage ROWS x 64 bf16 tile from row-major bf16 global (ld elements).
template<int ROWS>
__device__ __forceinline__ void stage64(short* lds, const unsigned short* g, int ld, int tid){
  #pragma unroll
  for (int j = 0; j < (ROWS*8)/256; ++j){
    int i = tid + j*256;
    int m = i >> 3, q = i & 7;
    s16x8 v = *(const s16x8*)(g + (size_t)m*ld + q*8);
    *(s16x8*)(lds + loff(m, q)) = v;
  }
}

// Stage ROWS x 64 tile from fp32 global, converting to bf16 (round-nearest).
template<int ROWS>
__device__ __forceinline__ void stage64f(short* lds, const float* g, int ld, int tid){
  #pragma unroll
  for (int j = 0; j < (ROWS*16)/256; ++j){
    int i = tid + j*256;
    int m = i >> 4, qq = i & 15;
    f32x4 v = *(const f32x4*)(g + (size_t)m*ld + qq*4);
    s16x4 h;
    #pragma unroll
    for (int r = 0; r < 4; ++r) h[r] = (short)f2us(v[r]);
    *(s16x4*)(lds + loff(m, qq >> 1) + (qq & 1)*4) = h;
  }
}

// A/B fragment from 64-wide tile: lane row (base + lane&15), granule ks*4+(lane>>4).
__device__ __forceinline__ s16x8 fragld(const short* lds, int row, int ks, int lane){
  return *(const s16x8*)(lds + loff(row + (lane & 15), ks*4 + (lane >> 4)));
}
// Same for 384-wide tiles (granule 0..47).
__device__ __forceinline__ s16x8 fragld384(const short* lds, int row, int ks, int lane){
  return *(const s16x8*)(lds + loff384(row + (lane & 15), ks*4 + (lane >> 4)));
}

// ---------------- K0: W2[c][t] = sum_i qw[i,c]*kw[i,t] (fp32) + u, b2v, qbkb
// Block 1 also zeroes cnt (saves a memset dispatch).
__global__ __launch_bounds__(384) void k_w2(
    const float* __restrict__ qw, const float* __restrict__ kw,
    const float* __restrict__ qb, const float* __restrict__ kb,
    float* __restrict__ w2f, float* __restrict__ u,
    float* __restrict__ b2v, float* __restrict__ qbkb,
    int* __restrict__ cnt)
{
  int c0 = blockIdx.x*2, t = threadIdx.x;
  if (blockIdx.x == 1){
    for (int i = t; i < 2048; i += 384) cnt[i] = 0;
  }
  float acc[2] = {0.f, 0.f};
  #pragma unroll 4
  for (int i = 0; i < 384; ++i){
    float kv = kw[i*384 + t];
    #pragma unroll
    for (int r = 0; r < 2; ++r)
      acc[r] = fmaf(qw[i*384 + c0 + r], kv, acc[r]);
  }
  #pragma unroll
  for (int r = 0; r < 2; ++r) w2f[(c0 + r)*384 + t] = acc[r];

  __shared__ float red[384];
  if (blockIdx.x == 0){
    float a = 0.f, bs = 0.f;
    #pragma unroll 8
    for (int i = 0; i < 384; ++i){
      a  = fmaf(qw[i*384 + t], kb[i], a);
      bs = fmaf(qb[i], kw[i*384 + t], bs);
    }
    u[t] = a; b2v[t] = bs;
    red[t] = qb[t] * kb[t];
    __syncthreads();
    for (int s = 192; s >= 3; s >>= 1){
      if (t < s) red[t] += red[t + s];
      __syncthreads();
    }
    if (t == 0) *qbkb = red[0] + red[1] + red[2];
  }
}

// ---------------- K1: q~ = (query @ W2 + b2) * scale, fp32 VALU. 8 rows/block.
// Output: scaled fp16 double split. qt[b][128][384]: rows g = f16(64 q~),
// rows 64+g = f16(2048*(64 q~ - hi)). Also computes bias[m] (k_bias folded in).
__global__ __launch_bounds__(384) void k_qtf(
    const float* __restrict__ query,   // [2048][384]
    const float* __restrict__ w2f,     // [c][t]
    const float* __restrict__ b2v,
    const float* __restrict__ u,
    const float* __restrict__ qbkb,
    unsigned short* __restrict__ qt,   // [B][128][384] fp16
    float* __restrict__ bias)          // [2048]
{
  __shared__ float qs[384*8];          // transposed: qs[c*8 + r]
  __shared__ float red2[384*8];
  int m0 = blockIdx.x * 8, t = threadIdx.x;
  #pragma unroll
  for (int r = 0; r < 8; ++r) qs[t*8 + r] = query[(size_t)(m0 + r)*384 + t];
  __syncthreads();
  float acc[8];
  float b2 = b2v[t];
  #pragma unroll
  for (int r = 0; r < 8; ++r) acc[r] = b2;
  #pragma unroll 4
  for (int c = 0; c < 384; ++c){
    float w = w2f[c*384 + t];
    f32x4 qa = *(const f32x4*)(qs + c*8);
    f32x4 qb4 = *(const f32x4*)(qs + c*8 + 4);
    #pragma unroll
    for (int r = 0; r < 4; ++r){
      acc[r]     = fmaf(qa[r],  w, acc[r]);
      acc[r + 4] = fmaf(qb4[r], w, acc[r + 4]);
    }
  }
  #pragma unroll
  for (int r = 0; r < 8; ++r){
    int m = m0 + r, b = m >> 6, g = m & 63;
    float v = acc[r] * (SCALE * 64.0f);
    unsigned short h = f2h(v);
    unsigned short md = f2h((v - h2f(h)) * 2048.0f);
    size_t base = ((size_t)b*128 + g)*384 + t;
    qt[base]                  = h;
    qt[base + (size_t)64*384] = md;
  }
  // bias[m] = SCALE*(query[m].u + qbkb), via LDS tree reduce.
  float uu = u[t];
  #pragma unroll
  for (int r = 0; r < 8; ++r) red2[r*384 + t] = qs[t*8 + r] * uu;
  __syncthreads();
  for (int s = 192; s >= 3; s >>= 1){
    if (t < s){
      #pragma unroll
      for (int r = 0; r < 8; ++r) red2[r*384 + t] += red2[r*384 + t + s];
    }
    __syncthreads();
  }
  if (t == 0){
    float qk = *qbkb;
    #pragma unroll
    for (int r = 0; r < 8; ++r)
      bias[m0 + r] = SCALE * (red2[r*384] + red2[r*384 + 1] + red2[r*384 + 2] + qk);
  }
}

// ---------------- K2: logits + softmax(g) + argmax, key streamed contiguously.
// 512 thr / 8 waves; wave = (kh2 = w>>2 K-half, gh = (w>>1)&1, cf = w&1).
// A-operand (q~ fp16 hi+mid) cached in regs: 24 s16x8/wave, loaded once from
// global qt. Bs [128][384] fp16: rows 0-63 kh, 64-127 km' (96KB). Per chunk:
// one MFMA region (24 B-reads + 72 MFMA / wave), K-half partial reduce via
// 16KB LDS scratch, online-softmax cross-gh combine. 4 barriers/chunk.
__global__ __launch_bounds__(512, 1) void k_attn(
    const unsigned short* __restrict__ qt,    // [B][128][384] fp16
    const float* __restrict__ key,            // [B][N][C] fp32
    const float* __restrict__ bias,           // [B*64]
    float* __restrict__ soft,                 // [B][64][N] fp32
    unsigned short* __restrict__ perm,        // [B*64][CAP]
    int* __restrict__ cnt)                    // [B*64]
{
  extern __shared__ short smem[];
  short* Bs = smem;                            // 128*384 fp16 = 96KB
  float* scratch = (float*)(smem + 128*384);   // [4][64][16] f32 = 16KB
  float* mxbuf   = scratch + 4096;             // [2][64]
  float* sumbuf  = mxbuf + 128;                // [2][64]
  float* bvbuf   = sumbuf + 128;               // [2][64]
  int*   bgbuf   = (int*)(bvbuf + 128);        // [2][64]

  int b = blockIdx.y, nb = blockIdx.x;         // nb: 0..7 -> rows nb*512..+512
  int tid = threadIdx.x, lane = tid & 63, w = tid >> 6;
  int kh2 = w >> 2, gh = (w >> 1) & 1, cf = w & 1;
  const unsigned short* qb = qt + (size_t)b*128*384;
  const float* kbase = key + ((size_t)b*N_ + nb*512)*C_;

  // A-fragments cached in registers: [split][gf][ks], K-range kh2*192..+192.
  s16x8 af[2][2][6];
  #pragma unroll
  for (int sp = 0; sp < 2; ++sp)
    #pragma unroll
    for (int gf = 0; gf < 2; ++gf)
      #pragma unroll
      for (int ks = 0; ks < 6; ++ks){
        int row = sp*64 + gh*32 + gf*16 + (lane & 15);
        int gran = (kh2*6 + ks)*4 + (lane >> 4);
        af[sp][gf][ks] = *(const s16x8*)(qb + (size_t)row*384 + gran*8);
      }

  // kv: one 64-row x 384-col fp32 chunk (96KB contiguous), linear order.
  f32x4 kv[12];
  auto load_kv = [&](int c){
    const float* src = kbase + (size_t)c*64*C_;
    #pragma unroll
    for (int j = 0; j < 12; ++j)
      kv[j] = *(const f32x4*)(src + (size_t)(tid + j*512)*4);
  };
  // split kv -> kh rows 0-63, km' rows 64-127 of Bs.
  auto stage = [&](){
    #pragma unroll
    for (int j = 0; j < 12; ++j){
      int d = tid + j*512;
      int m = (int)(((unsigned)d * 349526u) >> 25);    // d/96
      int cc = d - m*96;
      s16x4 hi, lo;
      #pragma unroll
      for (int r = 0; r < 4; ++r){
        float f = kv[j][r];
        unsigned short h = f2h(f);
        hi[r] = (short)h;
        lo[r] = (short)f2h((f - h2f(h)) * 2048.0f);
      }
      *(s16x4*)(Bs + loff384(m, cc >> 1) + (cc & 1)*4) = hi;
      *(s16x4*)(Bs + loff384(64 + m, cc >> 1) + (cc & 1)*4) = lo;
    }
  };

  float biasv[8];
  #pragma unroll
  for (int gf = 0; gf < 2; ++gf)
    #pragma unroll
    for (int r = 0; r < 4; ++r)
      biasv[gf*4 + r] = bias[b*64 + gh*32 + gf*16 + ((lane >> 4) << 2) + r];

  load_kv(0);
  stage();
  __syncthreads();                 // A(0): Bs chunk 0 ready
  load_kv(1);

  for (int c = 0; c < 8; ++c){
    f32x4 acc1[2][2] = {};         // [gf][ct]: qh.kh
    f32x4 acc2[2][2] = {};         //           qm.kh + qh.km
    __builtin_amdgcn_s_setprio(1);
    #pragma unroll
    for (int ks = 0; ks < 6; ++ks){
      int gks = kh2*6 + ks;
      #pragma unroll
      for (int ct = 0; ct < 2; ++ct){
        int colr = cf*32 + ct*16;
        s16x8 bh = fragld384(Bs, colr, gks, lane);
        s16x8 bm = fragld384(Bs, 64 + colr, gks, lane);
        #pragma unroll
        for (int gf = 0; gf < 2; ++gf){
          acc1[gf][ct] = mfma16h(af[0][gf][ks], bh, acc1[gf][ct]);
          acc2[gf][ct] = mfma16h(af[1][gf][ks], bh, acc2[gf][ct]);
          acc2[gf][ct] = mfma16h(af[0][gf][ks], bm, acc2[gf][ct]);
        }
      }
    }
    __builtin_amdgcn_s_setprio(0);
    // pre-combine splits (linear in K -> safe before K-half reduce)
    f32x4 vp[4];                   // [gf*2+ct]
    #pragma unroll
    for (int gf = 0; gf < 2; ++gf)
      #pragma unroll
      for (int ct = 0; ct < 2; ++ct)
        vp[gf*2 + ct] = acc1[gf][ct] + acc2[gf][ct] * 4.8828125e-4f;
    __syncthreads();               // D: all Bs reads done
    if (kh2 == 1){
      float* sc = scratch + (((gh*2 + cf)*64 + lane) << 4);
      #pragma unroll
      for (int i = 0; i < 4; ++i) *(f32x4*)(sc + i*4) = vp[i];
    }
    __syncthreads();               // E: partials visible
    float sgst[16];
    float mxl[2], suml[2], bvl[2]; int bgl[2];
    if (kh2 == 0){
      const float* sc = scratch + (((gh*2 + cf)*64 + lane) << 4);
      #pragma unroll
      for (int i = 0; i < 4; ++i) vp[i] += *(const f32x4*)(sc + i*4);
      #pragma unroll
      for (int ct = 0; ct < 2; ++ct){
        float mx = -3.4e38f;
        #pragma unroll
        for (int i = 0; i < 8; ++i){
          int gf = i >> 2, r = i & 3;
          float v = vp[gf*2 + ct][r] * 0.015625f + biasv[gf*4 + r];
          sgst[ct*8 + i] = v; mx = fmaxf(mx, v);
        }
        mx = fmaxf(mx, __shfl_xor(mx, 16));
        mx = fmaxf(mx, __shfl_xor(mx, 32));
        float sum = 0.f, bv = -3.4e38f; int bg = 0;
        #pragma unroll
        for (int i = 0; i < 8; ++i){
          int gf = i >> 2, r = i & 3;
          int g = gh*32 + gf*16 + ((lane >> 4) << 2) + r;
          float v = sgst[ct*8 + i];
          if (v > bv){ bv = v; bg = g; }
          float e = __expf(v - mx);
          sgst[ct*8 + i] = e; sum += e;
        }
        sum += __shfl_xor(sum, 16);
        sum += __shfl_xor(sum, 32);
        { float ov = __shfl_xor(bv, 16); int og = __shfl_xor(bg, 16);
          if (ov > bv || (ov == bv && og < bg)){ bv = ov; bg = og; } }
        { float ov = __shfl_xor(bv, 32); int og = __shfl_xor(bg, 32);
          if (ov > bv || (ov == bv && og < bg)){ bv = ov; bg = og; } }
        if (lane < 16){
          int ci = cf*32 + ct*16 + lane;
          mxbuf [gh*64 + ci] = mx;
          sumbuf[gh*64 + ci] = sum;
          bvbuf [gh*64 + ci] = bv;
          bgbuf [gh*64 + ci] = bg;
        }
        mxl[ct] = mx; suml[ct] = sum; bvl[ct] = bv; bgl[ct] = bg;
      }
    }
    __syncthreads();               // F: smallbufs visible
    if (kh2 == 0){
      #pragma unroll
      for (int ct = 0; ct < 2; ++ct){
        int ci = cf*32 + ct*16 + (lane & 15);
        int col = nb*512 + c*64 + ci;
        float omx  = mxbuf [(1 - gh)*64 + ci];
        float osum = sumbuf[(1 - gh)*64 + ci];
        float gmx  = fmaxf(mxl[ct], omx);
        float myw  = __expf(mxl[ct] - gmx);
        float tot  = suml[ct]*myw + osum*__expf(omx - gmx);
        float scalef = myw / tot;
        #pragma unroll
        for (int i = 0; i < 8; ++i){
          int gf = i >> 2, r = i & 3;
          int g = gh*32 + gf*16 + ((lane >> 4) << 2) + r;
          soft[(size_t)(b*64 + g)*N_ + col] = sgst[ct*8 + i] * scalef;
        }
        if (gh == 0 && lane < 16){
          float bv = bvl[ct]; int bg = bgl[ct];
          float obv = bvbuf[64 + cf*32 + ct*16 + lane];
          int   obg = bgbuf[64 + cf*32 + ct*16 + lane];
          if (obv > bv || (obv == bv && obg < bg)){ bv = obv; bg = obg; }
          int old = atomicAdd(&cnt[b*64 + bg], 1);
          if (old < CAP) perm[(size_t)(b*64 + bg)*CAP + old] = (unsigned short)col;
        }
      }
    }
    if (c < 7) stage();            // write chunk c+1 from kv
    if (c < 6) load_kv(c + 2);
    __syncthreads();               // A(c+1): Bs ready / all stores ordered
  }
}

// ---------------- K3: per-(b,g) gather-sum of assigned key rows -> aggs bf16
__global__ __launch_bounds__(384) void k_agg2(
    const float* __restrict__ key,
    const unsigned short* __restrict__ perm,
    const int* __restrict__ cnt,
    unsigned short* __restrict__ aggs)        // [2048][384] bf16
{
  __shared__ unsigned short pbuf[CAP];
  int m = blockIdx.x;            // b*64 + g
  int b = m >> 6, t = threadIdx.x;
  int cn = cnt[m];
  int rows = cn < CAP ? cn : CAP;
  for (int i = t; i < rows; i += 384) pbuf[i] = perm[(size_t)m*CAP + i];
  __syncthreads();
  const float* kb = key + (size_t)b*N_*C_ + t;
  float s = 0.f;
  int r = 0;
  for (; r + 8 <= rows; r += 8){
    float v0 = kb[(size_t)pbuf[r+0]*C_];
    float v1 = kb[(size_t)pbuf[r+1]*C_];
    float v2 = kb[(size_t)pbuf[r+2]*C_];
    float v3 = kb[(size_t)pbuf[r+3]*C_];
    float v4 = kb[(size_t)pbuf[r+4]*C_];
    float v5 = kb[(size_t)pbuf[r+5]*C_];
    float v6 = kb[(size_t)pbuf[r+6]*C_];
    float v7 = kb[(size_t)pbuf[r+7]*C_];
    s += ((v0 + v1) + (v2 + v3)) + ((v4 + v5) + (v6 + v7));
  }
  for (; r < rows; ++r) s += kb[(size_t)pbuf[r]*C_];
  aggs[(size_t)m*C_ + t] = f2us(s / ((float)cn + 1.f));
}

// ---------------- K4: out = A @ W^T + bias-term (mode 0: +cw*v_b -> bf16 tbuf;
//                                                 mode 1: +p_b   -> fp32 out)
// 64x64 tiles -> 192 blocks.
__global__ __launch_bounds__(256) void k_out384(
    const unsigned short* __restrict__ A,     // [2048][384] bf16
    const float* __restrict__ Wm,             // [384][384] fp32, [n][k]
    const float* __restrict__ bvec,           // [384] fp32
    const int* __restrict__ cnt,
    unsigned short* __restrict__ outb,
    float* __restrict__ outf,
    int mode)
{
  __shared__ short As[64*64];
  __shared__ short Bs[64*64];
  __shared__ float cwl[64];
  int m0 = blockIdx.y*64, nn0 = blockIdx.x*64;
  int tid = threadIdx.x, lane = tid & 63, w = tid >> 6;
  f32x4 acc[4] = {};
  for (int kk = 0; kk < 6; ++kk){
    stage64<64>(As, A + (size_t)m0*384 + kk*64, 384, tid);
    stage64f<64>(Bs, Wm + (size_t)nn0*384 + kk*64, 384, tid);
    __syncthreads();
    #pragma unroll
    for (int ks = 0; ks < 2; ++ks){
      s16x8 bfr = fragld(Bs, w*16, ks, lane);
      #pragma unroll
      for (int mi = 0; mi < 4; ++mi){
        s16x8 af = fragld(As, mi*16, ks, lane);
        acc[mi] = mfma16(af, bfr, acc[mi]);
      }
    }
    __syncthreads();
  }
  if (mode == 0 && tid < 64){
    float c = (float)cnt[m0 + tid];
    cwl[tid] = c / (c + 1.f);
  }
  __syncthreads();
  int n = nn0 + w*16 + (lane & 15);
  float bb = bvec[n];
  #pragma unroll
  for (int mi = 0; mi < 4; ++mi){
    #pragma unroll
    for (int r = 0; r < 4; ++r){
      int ml = mi*16 + ((lane >> 4) << 2) + r;
      float v = acc[mi][r];
      if (mode == 0){
        v += cwl[ml] * bb;
        outb[(size_t)(m0 + ml)*384 + n] = f2us(v);
      } else {
        outf[(size_t)(m0 + ml)*384 + n] = v + bb;
      }
    }
  }
}

extern "C" void kernel_launch(void* const* d_in, const int* in_sizes, int n_in,
                              void* d_out, int out_size, void* d_ws, size_t ws_size,
                              hipStream_t stream)
{
  const float* query = (const float*)d_in[0];
  const float* key   = (const float*)d_in[1];
  const float* qw    = (const float*)d_in[2];
  const float* qb    = (const float*)d_in[3];
  const float* kw    = (const float*)d_in[4];
  const float* kb    = (const float*)d_in[5];
  const float* vw    = (const float*)d_in[6];
  const float* vb    = (const float*)d_in[7];
  const float* pw    = (const float*)d_in[8];
  const float* pb    = (const float*)d_in[9];

  char* ws = (char*)d_ws;
  float* w2f           = (float*)(ws + 0);                  // 589824
  float* u             = (float*)(ws + 589824);             // 1536
  float* b2v           = (float*)(ws + 591360);             // 1536
  float* qbkb          = (float*)(ws + 592896);             // 256
  float* bias          = (float*)(ws + 593152);             // 8192
  unsigned short* qt   = (unsigned short*)(ws + 601344);    // 3145728 used (region 4718592)
  int*   cnt           = (int*)(ws + 5319936);              // 8192
  unsigned short* perm = (unsigned short*)(ws + 5328128);   // 8388608 (2048 buckets x CAP u16)
  unsigned short* aggs = (unsigned short*)(ws + 13716736);  // 1572864
  unsigned short* tbuf = (unsigned short*)(ws + 15289600);  // 1572864 -> ends 16862464

  float* outp = (float*)d_out;            // [2048][384]
  float* soft = outp + 786432;            // [2048][4096]

  static int attn_attr_set = 0;
  if (!attn_attr_set){
    hipFuncSetAttribute((const void*)k_attn,
                        hipFuncAttributeMaxDynamicSharedMemorySize, 116736);
    attn_attr_set = 1;
  }

  k_w2  <<<192, 384, 0, stream>>>(qw, kw, qb, kb, w2f, u, b2v, qbkb, cnt);
  k_qtf <<<256, 384, 0, stream>>>(query, w2f, b2v, u, qbkb, qt, bias);
  k_attn<<<dim3(8,32), 512, 116736, stream>>>(qt, key, bias, soft, perm, cnt);
  k_agg2<<<2048, 384, 0, stream>>>(key, perm, cnt, aggs);
  k_out384<<<dim3(6,32), 256, 0, stream>>>(aggs, vw, vb, cnt, tbuf, nullptr, 0);
  k_out384<<<dim3(6,32), 256, 0, stream>>>(tbuf, pw, pb, cnt, nullptr, outp, 1);
}

// Round 7
// 465.869 us; speedup vs baseline: 1.1267x; 1.1267x over previous
//
#include <hip/hip_runtime.h>
#include <hip/hip_bf16.h>
#include <stdint.h>
#include <stddef.h>

// GroupViT assign-attention, MI355X/gfx950. All I/O fp32.
// Identities:
//   raw_attn = (q @ k_w) . key_n + q . k_b          -> no k-projection GEMM
//   fwd attn value = one_hot(argmax)/(cnt+1)        -> no v-projection GEMM
//   out = aggs @ (pw@vw)^T + cw*(pw@vb) + pb        -> ONE output GEMM (R10)
// R2 lesson: runtime index into register array kills SROA -> scratch spill.
// R3 lesson: 12.6M fp32 atomicAdds cost >100us -> counting-sort (perm) + gather.
// R5 lesson: contiguous key streaming fixes DRAM page locality; fp16 double
//   split (scheme err ~6e-8) is the only split that doesn't flip argmax ties.
// R9 lesson: k_attn ~120us is INSENSITIVE to LDS/compute micro-structure;
//   half-wave epilogue serialization (kh2 split) regressed it 121->127.
//   Reverted to R8 form; k_attn is frozen.
// R10 (this round): fold W4=pw@vw + pvb=pw@vb precompute into k_w2's idle
//   blocks (192-384); single k_out384 (A@W4^T + cw*pvb + pb) -> one GEMM
//   launch + no tbuf bf16 intermediate.

using bf16 = __hip_bfloat16;
typedef __attribute__((ext_vector_type(4))) float f32x4;
typedef __attribute__((ext_vector_type(8))) short s16x8;
typedef __attribute__((ext_vector_type(4))) short s16x4;
typedef _Float16 f16x8 __attribute__((ext_vector_type(8)));

#define B_  32
#define G_  64
#define N_  4096
#define C_  384
#define CAP 2048   // perm bucket capacity (counts ~64 avg; 2048 is >>max)
#define SCALE 0.05103103630798287f   // 384^-0.5

__device__ __forceinline__ float us2f(unsigned short u){
  union { unsigned int i; float f; } v; v.i = ((unsigned int)u) << 16; return v.f;
}
__device__ __forceinline__ unsigned short f2us(float f){
  bf16 h = __float2bfloat16(f);
  return __builtin_bit_cast(unsigned short, h);
}
// fp16 (IEEE half) helpers, RNE.
__device__ __forceinline__ unsigned short f2h(float f){
  _Float16 h = (_Float16)f;
  return __builtin_bit_cast(unsigned short, h);
}
__device__ __forceinline__ float h2f(unsigned short u){
  return (float)__builtin_bit_cast(_Float16, u);
}

__device__ __forceinline__ f32x4 mfma16(s16x8 a, s16x8 b, f32x4 c){
  return __builtin_amdgcn_mfma_f32_16x16x32_bf16(a, b, c, 0, 0, 0);
}
__device__ __forceinline__ f32x4 mfma16h(s16x8 a, s16x8 b, f32x4 c){
  return __builtin_amdgcn_mfma_f32_16x16x32_f16(
      __builtin_bit_cast(f16x8, a), __builtin_bit_cast(f16x8, b), c, 0, 0, 0);
}

// Swizzled LDS layouts: 16B granule q XOR'd with row&7 (bank-spread).
__device__ __forceinline__ int loff(int m, int q){ return m*64 + ((q ^ (m & 7)) << 3); }
__device__ __forceinline__ int loff384(int m, int q){ return m*384 + ((q ^ (m & 7)) << 3); }

// Stage ROWS x 64 bf16 tile from row-major bf16 global (ld elements).
template<int ROWS>
__device__ __forceinline__ void stage64(short* lds, const unsigned short* g, int ld, int tid){
  #pragma unroll
  for (int j = 0; j < (ROWS*8)/256; ++j){
    int i = tid + j*256;
    int m = i >> 3, q = i & 7;
    s16x8 v = *(const s16x8*)(g + (size_t)m*ld + q*8);
    *(s16x8*)(lds + loff(m, q)) = v;
  }
}

// Stage ROWS x 64 tile from fp32 global, converting to bf16 (round-nearest).
template<int ROWS>
__device__ __forceinline__ void stage64f(short* lds, const float* g, int ld, int tid){
  #pragma unroll
  for (int j = 0; j < (ROWS*16)/256; ++j){
    int i = tid + j*256;
    int m = i >> 4, qq = i & 15;
    f32x4 v = *(const f32x4*)(g + (size_t)m*ld + qq*4);
    s16x4 h;
    #pragma unroll
    for (int r = 0; r < 4; ++r) h[r] = (short)f2us(v[r]);
    *(s16x4*)(lds + loff(m, qq >> 1) + (qq & 1)*4) = h;
  }
}

// A/B fragment from 64-wide tile: lane row (base + lane&15), granule ks*4+(lane>>4).
__device__ __forceinline__ s16x8 fragld(const short* lds, int row, int ks, int lane){
  return *(const s16x8*)(lds + loff(row + (lane & 15), ks*4 + (lane >> 4)));
}
// Same for 384-wide tiles (granule 0..47).
__device__ __forceinline__ s16x8 fragld384(const short* lds, int row, int ks, int lane){
  return *(const s16x8*)(lds + loff384(row + (lane & 15), ks*4 + (lane >> 4)));
}

// ---------------- K0: blocks 0-191: W2[c][t] = sum_i qw[i,c]*kw[i,t] (+u,b2v,
// qbkb in block 0; cnt zeroing in block 1). Blocks 192-383: W4 = pw@vw.
// Block 384: pvb = pw@vb.
__global__ __launch_bounds__(384) void k_w2(
    const float* __restrict__ qw, const float* __restrict__ kw,
    const float* __restrict__ qb, const float* __restrict__ kb,
    const float* __restrict__ vw, const float* __restrict__ pw,
    const float* __restrict__ vb,
    float* __restrict__ w2f, float* __restrict__ W4,
    float* __restrict__ u, float* __restrict__ b2v,
    float* __restrict__ qbkb, float* __restrict__ pvb,
    int* __restrict__ cnt)
{
  __shared__ float red[384];
  int t = threadIdx.x, bx = blockIdx.x;
  if (bx < 192){
    int c0 = bx*2;
    float acc[2] = {0.f, 0.f};
    #pragma unroll 4
    for (int i = 0; i < 384; ++i){
      float kv = kw[i*384 + t];
      acc[0] = fmaf(qw[i*384 + c0],     kv, acc[0]);
      acc[1] = fmaf(qw[i*384 + c0 + 1], kv, acc[1]);
    }
    w2f[c0*384 + t] = acc[0];
    w2f[(c0 + 1)*384 + t] = acc[1];
    if (bx == 1){
      for (int i = t; i < 2048; i += 384) cnt[i] = 0;
    }
    if (bx == 0){
      float a = 0.f, bs = 0.f;
      #pragma unroll 8
      for (int i = 0; i < 384; ++i){
        a  = fmaf(qw[i*384 + t], kb[i], a);
        bs = fmaf(qb[i], kw[i*384 + t], bs);
      }
      u[t] = a; b2v[t] = bs;
      red[t] = qb[t] * kb[t];
      __syncthreads();
      for (int s = 192; s >= 3; s >>= 1){
        if (t < s) red[t] += red[t + s];
        __syncthreads();
      }
      if (t == 0) *qbkb = red[0] + red[1] + red[2];
    }
  } else if (bx < 384){
    int n0 = (bx - 192)*2;
    float acc[2] = {0.f, 0.f};
    #pragma unroll 4
    for (int j = 0; j < 384; ++j){
      float vv = vw[j*384 + t];
      acc[0] = fmaf(pw[n0*384 + j],       vv, acc[0]);
      acc[1] = fmaf(pw[(n0 + 1)*384 + j], vv, acc[1]);
    }
    W4[n0*384 + t] = acc[0];
    W4[(n0 + 1)*384 + t] = acc[1];
  } else {
    float a = 0.f;
    #pragma unroll 8
    for (int i = 0; i < 384; ++i)
      a = fmaf(pw[t*384 + i], vb[i], a);
    pvb[t] = a;
  }
}

// ---------------- K1: q~ = (query @ W2 + b2) * scale, fp32 VALU. 8 rows/block.
// Output: scaled fp16 double split. qt[b][128][384]: rows g = f16(64 q~),
// rows 64+g = f16(2048*(64 q~ - hi)). Also computes bias[m] (k_bias folded in).
__global__ __launch_bounds__(384) void k_qtf(
    const float* __restrict__ query,   // [2048][384]
    const float* __restrict__ w2f,     // [c][t]
    const float* __restrict__ b2v,
    const float* __restrict__ u,
    const float* __restrict__ qbkb,
    unsigned short* __restrict__ qt,   // [B][128][384] fp16
    float* __restrict__ bias)          // [2048]
{
  __shared__ float qs[384*8];          // transposed: qs[c*8 + r]
  __shared__ float red2[384*8];
  int m0 = blockIdx.x * 8, t = threadIdx.x;
  #pragma unroll
  for (int r = 0; r < 8; ++r) qs[t*8 + r] = query[(size_t)(m0 + r)*384 + t];
  __syncthreads();
  float acc[8];
  float b2 = b2v[t];
  #pragma unroll
  for (int r = 0; r < 8; ++r) acc[r] = b2;
  #pragma unroll 4
  for (int c = 0; c < 384; ++c){
    float w = w2f[c*384 + t];
    f32x4 qa = *(const f32x4*)(qs + c*8);
    f32x4 qb4 = *(const f32x4*)(qs + c*8 + 4);
    #pragma unroll
    for (int r = 0; r < 4; ++r){
      acc[r]     = fmaf(qa[r],  w, acc[r]);
      acc[r + 4] = fmaf(qb4[r], w, acc[r + 4]);
    }
  }
  #pragma unroll
  for (int r = 0; r < 8; ++r){
    int m = m0 + r, b = m >> 6, g = m & 63;
    float v = acc[r] * (SCALE * 64.0f);
    unsigned short h = f2h(v);
    unsigned short md = f2h((v - h2f(h)) * 2048.0f);
    size_t base = ((size_t)b*128 + g)*384 + t;
    qt[base]                  = h;
    qt[base + (size_t)64*384] = md;
  }
  // bias[m] = SCALE*(query[m].u + qbkb), via LDS tree reduce.
  float uu = u[t];
  #pragma unroll
  for (int r = 0; r < 8; ++r) red2[r*384 + t] = qs[t*8 + r] * uu;
  __syncthreads();
  for (int s = 192; s >= 3; s >>= 1){
    if (t < s){
      #pragma unroll
      for (int r = 0; r < 8; ++r) red2[r*384 + t] += red2[r*384 + t + s];
    }
    __syncthreads();
  }
  if (t == 0){
    float qk = *qbkb;
    #pragma unroll
    for (int r = 0; r < 8; ++r)
      bias[m0 + r] = SCALE * (red2[r*384] + red2[r*384 + 1] + red2[r*384 + 2] + qk);
  }
}

// ---------------- K2: logits + softmax(g) + argmax, key streamed contiguously.
// 512 thr / 8 waves; wave = (gh = w>>2 group-half, cf = w&3 col-frag).
// As: q~ fp16 hi+mid splits, 128 x 384 (96KB, staged ONCE per block).
// Bs: 64 key rows x 384 fp16, kh then km'(x2048) time-muxed (48KB).
// Persistent: block owns 512 key rows = 8 chunks of 64. Cross-half softmax
// combine: SINGLE barrier, online-softmax rescale. 4 barriers/chunk.
// FROZEN since R8 (492us config) -- do not micro-restructure (R9 lesson).
__global__ __launch_bounds__(512) void k_attn(
    const unsigned short* __restrict__ qt,    // [B][128][384] fp16
    const float* __restrict__ key,            // [B][N][C] fp32
    const float* __restrict__ bias,           // [B*64]
    float* __restrict__ soft,                 // [B][64][N] fp32
    unsigned short* __restrict__ perm,        // [B*64][CAP]
    int* __restrict__ cnt)                    // [B*64]
{
  extern __shared__ short smem[];
  short* As = smem;                           // 128*384 fp16 = 96KB
  short* Bs = smem + 128*384;                 // 64*384 fp16 = 48KB
  float* mxbuf  = (float*)(smem + (128+64)*384);   // [2][64]
  float* sumbuf = mxbuf + 128;                     // [2][64]
  float* bvbuf  = sumbuf + 128;                    // [2][64]
  int*   bgbuf  = (int*)(bvbuf + 128);             // [2][64]

  int b = blockIdx.y, nb = blockIdx.x;        // nb: 0..7 -> rows nb*512..+512
  int tid = threadIdx.x, lane = tid & 63, w = tid >> 6;
  int gh = w >> 2, cf = w & 3;
  const unsigned short* qb = qt + (size_t)b*128*384;
  const float* kbase = key + ((size_t)b*N_ + nb*512)*C_;

  // kv: one 64-row x 384-col fp32 chunk (96KB contiguous), linear order.
  f32x4 kv[12];
  auto load_kv = [&](int c){
    const float* src = kbase + (size_t)c*64*C_;
    #pragma unroll
    for (int j = 0; j < 12; ++j)
      kv[j] = *(const f32x4*)(src + (size_t)(tid + j*512)*4);
  };
  load_kv(0);

  // Stage As once (6144 granules / 512 thr = 12 each), swizzled.
  #pragma unroll
  for (int j = 0; j < 12; ++j){
    int i = tid + j*512;
    int m = (int)(((unsigned)i * 349526u) >> 24);   // i/48 (exact for i<2^17)
    int q = i - m*48;
    s16x8 v = *(const s16x8*)(qb + (size_t)m*384 + q*8);
    *(s16x8*)(As + loff384(m, q)) = v;
  }

  // Hoist bias: 8 values per lane (this wave's groups).
  float biasv[8];
  #pragma unroll
  for (int i = 0; i < 8; ++i)
    biasv[i] = bias[b*64 + gh*32 + (i >> 2)*16 + ((lane >> 4) << 2) + (i & 3)];

  for (int c = 0; c < 8; ++c){
    f32x4 acc1[2] = {};
    f32x4 acc2[2] = {};
    // split kv -> kh straight to Bs, km' = 2048*(k-kh) kept in regs
    s16x4 lo[12];
    #pragma unroll
    for (int j = 0; j < 12; ++j){
      int d = tid + j*512;                             // f32x4 linear index
      int m = (int)(((unsigned)d * 349526u) >> 25);    // d/96
      int cc = d - m*96;
      s16x4 hi;
      #pragma unroll
      for (int r = 0; r < 4; ++r){
        float f = kv[j][r];
        unsigned short h = f2h(f);
        hi[r] = (short)h;
        lo[j][r] = (short)f2h((f - h2f(h)) * 2048.0f);
      }
      *(s16x4*)(Bs + loff384(m, cc >> 1) + (cc & 1)*4) = hi;
    }
    __syncthreads();                 // A: As + Bs-kh visible
    if (c < 7) load_kv(c + 1);       // prefetch flies across both passes
    // pass 1: qh.kh -> acc1 ; qm.kh -> acc2
    __builtin_amdgcn_s_setprio(1);
    #pragma unroll
    for (int ks = 0; ks < 12; ++ks){
      s16x8 bfr = fragld384(Bs, cf*16, ks, lane);
      #pragma unroll
      for (int gf = 0; gf < 2; ++gf){
        s16x8 a0 = fragld384(As, gh*32 + gf*16, ks, lane);
        s16x8 a1 = fragld384(As, 64 + gh*32 + gf*16, ks, lane);
        acc1[gf] = mfma16h(a0, bfr, acc1[gf]);
        acc2[gf] = mfma16h(a1, bfr, acc2[gf]);
      }
    }
    __builtin_amdgcn_s_setprio(0);
    __syncthreads();                 // B: pass-1 reads done, Bs reusable
    #pragma unroll
    for (int j = 0; j < 12; ++j){
      int d = tid + j*512;
      int m = (int)(((unsigned)d * 349526u) >> 25);
      int cc = d - m*96;
      *(s16x4*)(Bs + loff384(m, cc >> 1) + (cc & 1)*4) = lo[j];
    }
    __syncthreads();                 // C: Bs-km visible
    // pass 2: qh.km -> acc2
    __builtin_amdgcn_s_setprio(1);
    #pragma unroll
    for (int ks = 0; ks < 12; ++ks){
      s16x8 bfr = fragld384(Bs, cf*16, ks, lane);
      #pragma unroll
      for (int gf = 0; gf < 2; ++gf){
        s16x8 a0 = fragld384(As, gh*32 + gf*16, ks, lane);
        acc2[gf] = mfma16h(a0, bfr, acc2[gf]);
      }
    }
    __builtin_amdgcn_s_setprio(0);

    // Epilogue: wave holds 32 groups x 16 cols; ONE-barrier online-softmax
    // combine across group-halves.
    int col = nb*512 + c*64 + cf*16 + (lane & 15);
    float sg[8];
    float mx = -3.4e38f;
    #pragma unroll
    for (int i = 0; i < 8; ++i){
      float v = (acc1[i >> 2][i & 3] + acc2[i >> 2][i & 3] * 4.8828125e-4f)
                * 0.015625f + biasv[i];
      sg[i] = v; mx = fmaxf(mx, v);
    }
    mx = fmaxf(mx, __shfl_xor(mx, 16));
    mx = fmaxf(mx, __shfl_xor(mx, 32));
    float sum = 0.f, bv = -3.4e38f; int bg = 0;
    #pragma unroll
    for (int i = 0; i < 8; ++i){
      int g = gh*32 + (i >> 2)*16 + ((lane >> 4) << 2) + (i & 3);
      float v = sg[i];
      if (v > bv){ bv = v; bg = g; }
      float e = __expf(v - mx);          // local-max based; rescaled below
      sg[i] = e; sum += e;
    }
    sum += __shfl_xor(sum, 16);
    sum += __shfl_xor(sum, 32);
    { float ov = __shfl_xor(bv, 16); int og = __shfl_xor(bg, 16);
      if (ov > bv || (ov == bv && og < bg)){ bv = ov; bg = og; } }
    { float ov = __shfl_xor(bv, 32); int og = __shfl_xor(bg, 32);
      if (ov > bv || (ov == bv && og < bg)){ bv = ov; bg = og; } }
    if (lane < 16){
      mxbuf [gh*64 + cf*16 + lane] = mx;
      sumbuf[gh*64 + cf*16 + lane] = sum;
      bvbuf [gh*64 + cf*16 + lane] = bv;
      bgbuf [gh*64 + cf*16 + lane] = bg;
    }
    __syncthreads();                 // F: single combine barrier
    float omx  = mxbuf [(1 - gh)*64 + cf*16 + (lane & 15)];
    float osum = sumbuf[(1 - gh)*64 + cf*16 + (lane & 15)];
    float gmx  = fmaxf(mx, omx);
    float myw  = __expf(mx - gmx);
    float tot  = sum*myw + osum*__expf(omx - gmx);
    float scalef = myw / tot;
    #pragma unroll
    for (int i = 0; i < 8; ++i){
      int g = gh*32 + (i >> 2)*16 + ((lane >> 4) << 2) + (i & 3);
      soft[(size_t)(b*64 + g)*N_ + col] = sg[i] * scalef;
    }
    if (gh == 0 && lane < 16){
      float obv = bvbuf[64 + cf*16 + lane];
      int   obg = bgbuf[64 + cf*16 + lane];
      if (obv > bv || (obv == bv && obg < bg)){ bv = obv; bg = obg; }
      int old = atomicAdd(&cnt[b*64 + bg], 1);
      if (old < CAP) perm[(size_t)(b*64 + bg)*CAP + old] = (unsigned short)col;
    }
  }
}

// ---------------- K3: per-(b,g) gather-sum of assigned key rows -> aggs bf16
__global__ __launch_bounds__(384) void k_agg2(
    const float* __restrict__ key,
    const unsigned short* __restrict__ perm,
    const int* __restrict__ cnt,
    unsigned short* __restrict__ aggs)        // [2048][384] bf16
{
  __shared__ unsigned short pbuf[CAP];
  int m = blockIdx.x;            // b*64 + g
  int b = m >> 6, t = threadIdx.x;
  int cn = cnt[m];
  int rows = cn < CAP ? cn : CAP;
  for (int i = t; i < rows; i += 384) pbuf[i] = perm[(size_t)m*CAP + i];
  __syncthreads();
  const float* kb = key + (size_t)b*N_*C_ + t;
  float s = 0.f;
  int r = 0;
  for (; r + 8 <= rows; r += 8){
    float v0 = kb[(size_t)pbuf[r+0]*C_];
    float v1 = kb[(size_t)pbuf[r+1]*C_];
    float v2 = kb[(size_t)pbuf[r+2]*C_];
    float v3 = kb[(size_t)pbuf[r+3]*C_];
    float v4 = kb[(size_t)pbuf[r+4]*C_];
    float v5 = kb[(size_t)pbuf[r+5]*C_];
    float v6 = kb[(size_t)pbuf[r+6]*C_];
    float v7 = kb[(size_t)pbuf[r+7]*C_];
    s += ((v0 + v1) + (v2 + v3)) + ((v4 + v5) + (v6 + v7));
  }
  for (; r < rows; ++r) s += kb[(size_t)pbuf[r]*C_];
  aggs[(size_t)m*C_ + t] = f2us(s / ((float)cn + 1.f));
}

// ---------------- K4: out = A @ W4^T + cw*pvb + pb (fp32 out), 64x64 tiles.
__global__ __launch_bounds__(256) void k_out384(
    const unsigned short* __restrict__ A,     // aggs [2048][384] bf16
    const float* __restrict__ W4,             // [384][384] fp32, [n][k]
    const float* __restrict__ pvb,            // [384] fp32
    const float* __restrict__ pb,             // [384] fp32
    const int* __restrict__ cnt,
    float* __restrict__ outf)
{
  __shared__ short As[64*64];
  __shared__ short Bs[64*64];
  __shared__ float cwl[64];
  int m0 = blockIdx.y*64, nn0 = blockIdx.x*64;
  int tid = threadIdx.x, lane = tid & 63, w = tid >> 6;
  f32x4 acc[4] = {};
  for (int kk = 0; kk < 6; ++kk){
    stage64<64>(As, A + (size_t)m0*384 + kk*64, 384, tid);
    stage64f<64>(Bs, W4 + (size_t)nn0*384 + kk*64, 384, tid);
    __syncthreads();
    #pragma unroll
    for (int ks = 0; ks < 2; ++ks){
      s16x8 bfr = fragld(Bs, w*16, ks, lane);
      #pragma unroll
      for (int mi = 0; mi < 4; ++mi){
        s16x8 af = fragld(As, mi*16, ks, lane);
        acc[mi] = mfma16(af, bfr, acc[mi]);
      }
    }
    __syncthreads();
  }
  if (tid < 64){
    float c = (float)cnt[m0 + tid];
    cwl[tid] = c / (c + 1.f);
  }
  __syncthreads();
  int n = nn0 + w*16 + (lane & 15);
  float bb = pb[n], pv = pvb[n];
  #pragma unroll
  for (int mi = 0; mi < 4; ++mi){
    #pragma unroll
    for (int r = 0; r < 4; ++r){
      int ml = mi*16 + ((lane >> 4) << 2) + r;
      outf[(size_t)(m0 + ml)*384 + n] = acc[mi][r] + cwl[ml]*pv + bb;
    }
  }
}

extern "C" void kernel_launch(void* const* d_in, const int* in_sizes, int n_in,
                              void* d_out, int out_size, void* d_ws, size_t ws_size,
                              hipStream_t stream)
{
  const float* query = (const float*)d_in[0];
  const float* key   = (const float*)d_in[1];
  const float* qw    = (const float*)d_in[2];
  const float* qb    = (const float*)d_in[3];
  const float* kw    = (const float*)d_in[4];
  const float* kb    = (const float*)d_in[5];
  const float* vw    = (const float*)d_in[6];
  const float* vb    = (const float*)d_in[7];
  const float* pw    = (const float*)d_in[8];
  const float* pb    = (const float*)d_in[9];

  char* ws = (char*)d_ws;
  float* w2f           = (float*)(ws + 0);                  // 589824
  float* W4            = (float*)(ws + 589824);             // 589824
  float* u             = (float*)(ws + 1179648);            // 1536
  float* b2v           = (float*)(ws + 1181184);            // 1536
  float* qbkb          = (float*)(ws + 1182720);            // 256
  float* pvb           = (float*)(ws + 1182976);            // 1536
  float* bias          = (float*)(ws + 1184512);            // 8192
  unsigned short* qt   = (unsigned short*)(ws + 1192704);   // 3145728
  int*   cnt           = (int*)(ws + 4338432);              // 8192
  unsigned short* perm = (unsigned short*)(ws + 4346624);   // 8388608
  unsigned short* aggs = (unsigned short*)(ws + 12735232);  // 1572864 -> ends 14308096

  float* outp = (float*)d_out;            // [2048][384]
  float* soft = outp + 786432;            // [2048][4096]

  static int attn_attr_set = 0;
  if (!attn_attr_set){
    hipFuncSetAttribute((const void*)k_attn,
                        hipFuncAttributeMaxDynamicSharedMemorySize, 149504);
    attn_attr_set = 1;
  }

  k_w2  <<<385, 384, 0, stream>>>(qw, kw, qb, kb, vw, pw, vb,
                                  w2f, W4, u, b2v, qbkb, pvb, cnt);
  k_qtf <<<256, 384, 0, stream>>>(query, w2f, b2v, u, qbkb, qt, bias);
  k_attn<<<dim3(8,32), 512, 149504, stream>>>(qt, key, bias, soft, perm, cnt);
  k_agg2<<<2048, 384, 0, stream>>>(key, perm, cnt, aggs);
  k_out384<<<dim3(6,32), 256, 0, stream>>>(aggs, W4, pvb, pb, cnt, outp);
}